// Round 6
// baseline (470.851 us; speedup 1.0000x reference)
//
#include <hip/hip_runtime.h>
#include <math.h>

#define BB 16
#define TT 2048
#define FF 512
#define CC 256
#define NEG 10
#define NSTEPS 12
#define COPIES 11
#define MM (BB * TT)

// ---------------- Kernel 1: tl = true_latent @ Wl + bl  (f32 GEMM 32768x512x256)
// 128x128 tile, 256 threads, 8x8 outputs/thread, BK=16, k-major A, reg prefetch.
__global__ __launch_bounds__(256) void proj_gemm_kernel(
    const float* __restrict__ A,     // [MM, FF] row-major
    const float* __restrict__ W,     // [FF, CC] row-major
    const float* __restrict__ bias,  // [CC]
    float* __restrict__ Out) {       // [MM, CC]
  __shared__ __align__(16) float As[16][132];  // k-major; 132*4=528B row stride (16B mult)
  __shared__ __align__(16) float Bs[16][128];
  const int tid = threadIdx.x;
  const int bm = blockIdx.x * 128;
  const int bn = blockIdx.y * 128;
  const int tx = tid & 15;   // n-tile 0..15
  const int ty = tid >> 4;   // m-tile 0..15
  const int am = tid >> 1;
  const int ak = (tid & 1) * 8;
  const int bk = tid >> 5;          // 0..7
  const int bc = (tid & 31) * 4;    // 0..124
  float acc[8][8] = {};

  const float* Ap = &A[(size_t)(bm + am) * FF + ak];
  const float* Bp = &W[(size_t)bk * CC + bn + bc];
  float4 pa0 = *reinterpret_cast<const float4*>(Ap);
  float4 pa1 = *reinterpret_cast<const float4*>(Ap + 4);
  float4 pb0 = *reinterpret_cast<const float4*>(Bp);
  float4 pb1 = *reinterpret_cast<const float4*>(Bp + 8 * CC);

  for (int kt = 0; kt < FF / 16; ++kt) {
    __syncthreads();
    As[ak + 0][am] = pa0.x; As[ak + 1][am] = pa0.y;
    As[ak + 2][am] = pa0.z; As[ak + 3][am] = pa0.w;
    As[ak + 4][am] = pa1.x; As[ak + 5][am] = pa1.y;
    As[ak + 6][am] = pa1.z; As[ak + 7][am] = pa1.w;
    *reinterpret_cast<float4*>(&Bs[bk][bc]) = pb0;
    *reinterpret_cast<float4*>(&Bs[bk + 8][bc]) = pb1;
    __syncthreads();
    if (kt + 1 < FF / 16) {  // prefetch next k-tile while computing this one
      const float* Apn = Ap + (kt + 1) * 16;
      const float* Bpn = Bp + (size_t)(kt + 1) * 16 * CC;
      pa0 = *reinterpret_cast<const float4*>(Apn);
      pa1 = *reinterpret_cast<const float4*>(Apn + 4);
      pb0 = *reinterpret_cast<const float4*>(Bpn);
      pb1 = *reinterpret_cast<const float4*>(Bpn + 8 * CC);
    }
#pragma unroll
    for (int kk = 0; kk < 16; ++kk) {
      const float4 a0 = *reinterpret_cast<const float4*>(&As[kk][ty * 8]);
      const float4 a1 = *reinterpret_cast<const float4*>(&As[kk][ty * 8 + 4]);
      const float4 b0 = *reinterpret_cast<const float4*>(&Bs[kk][tx * 8]);
      const float4 b1 = *reinterpret_cast<const float4*>(&Bs[kk][tx * 8 + 4]);
      const float av[8] = {a0.x, a0.y, a0.z, a0.w, a1.x, a1.y, a1.z, a1.w};
      const float bv[8] = {b0.x, b0.y, b0.z, b0.w, b1.x, b1.y, b1.z, b1.w};
#pragma unroll
      for (int i = 0; i < 8; ++i)
#pragma unroll
        for (int j = 0; j < 8; ++j) acc[i][j] = fmaf(av[i], bv[j], acc[i][j]);
    }
  }
  float bz[8];
#pragma unroll
  for (int j = 0; j < 8; ++j) bz[j] = bias[bn + tx * 8 + j];
#pragma unroll
  for (int i = 0; i < 8; ++i) {
    float4 o0, o1;
    o0.x = acc[i][0] + bz[0]; o0.y = acc[i][1] + bz[1];
    o0.z = acc[i][2] + bz[2]; o0.w = acc[i][3] + bz[3];
    o1.x = acc[i][4] + bz[4]; o1.y = acc[i][5] + bz[5];
    o1.z = acc[i][6] + bz[6]; o1.w = acc[i][7] + bz[7];
    float* orow = &Out[(size_t)(bm + ty * 8 + i) * CC + bn + tx * 8];
    *reinterpret_cast<float4*>(orow) = o0;
    *reinterpret_cast<float4*>(orow + 4) = o1;
  }
}

// ---------------- Kernel 2: per-(b, 64 consecutive t') block.
// Thread (tloc, ih, kg2): t' = tp0+tloc, i-half ih (6 steps), k-half kg2 (128 floats).
// 66 dot accumulators/thread (~180 VGPR, under the 256 cliff). ctx rows from LDS
// (XOR-swizzled, staged once per block); target rows from global (tl is L2-resident).
// Reduce: acc over kg2 (shfl_xor 1), step-half contribs over ih (shfl_xor 2).
#define TP 64
#define NROWS (TP + COPIES)  // 75 ctx rows: [tp0-11, tp0+63]
#define IH 6                 // steps per i-half
__global__ __launch_bounds__(256) void cpc_loss_kernel(
    const float* __restrict__ ctx,  // [BB, TT, CC]
    const float* __restrict__ tl,   // [BB, TT, CC]
    const int* __restrict__ negs,   // [BB, NEG, TT]
    const float* __restrict__ Ws,   // [NSTEPS]
    const float* __restrict__ bs,   // [NSTEPS]
    float* __restrict__ partials) { // [MM]
  __shared__ __align__(16) float lds[NROWS * CC];  // 76.8 KB
  const int tid = threadIdx.x;
  const int tloc = tid >> 2;        // 0..63
  const int ih = (tid >> 1) & 1;    // i-half
  const int kg2 = tid & 1;          // k-half
  const int b = blockIdx.x >> 5;           // / (TT/TP)
  const int tp0 = (blockIdx.x & 31) << 6;  // * TP
  const int tp = tp0 + tloc;

  // Stage ctx window; float4-index XOR-swizzled by (row&7)
  for (int idx = tid; idx < NROWS * (CC / 4); idx += 256) {
    const int r = idx >> 6;
    const int c4 = idx & 63;
    const int t = tp0 - COPIES + r;
    float4 v = make_float4(0.f, 0.f, 0.f, 0.f);
    if (t >= 0) v = *reinterpret_cast<const float4*>(&ctx[((size_t)b * TT + t) * CC + c4 * 4]);
    *reinterpret_cast<float4*>(&lds[r * CC + ((c4 ^ (r & 7)) << 2)]) = v;
  }

  // Target byte offsets for this thread's k-half (tl = 32MB, 32-bit offsets fit)
  unsigned off[COPIES];
  off[0] = (unsigned)(((size_t)b * TT + tp) * CC + kg2 * 128) * 4u;
#pragma unroll
  for (int n = 0; n < NEG; ++n) {
    const int u = negs[((size_t)b * NEG + n) * TT + tp];
    off[n + 1] = (unsigned)(((size_t)b * TT + u) * CC + kg2 * 128) * 4u;
  }
  const char* tlb = (const char*)tl;

  // This thread's 6 ctx LDS rows (row = tloc + 11 - i, i = ih*6 + ii)
  int rbase[IH], rsw[IH];
#pragma unroll
  for (int ii = 0; ii < IH; ++ii) {
    const int r = tloc + COPIES - (ih * IH + ii);
    rbase[ii] = r * CC;
    rsw[ii] = r & 7;
  }
  const int kc0 = kg2 * 32;  // float4 base of this k-half

  float acc[IH][COPIES] = {};
  float tsum[COPIES] = {};
  __syncthreads();

  for (int c4 = 0; c4 < 32; ++c4) {  // 32 float4 chunks = this thread's 128-float k-half
    float4 tg[COPIES];
#pragma unroll
    for (int cp = 0; cp < COPIES; ++cp)
      tg[cp] = *reinterpret_cast<const float4*>(tlb + off[cp] + c4 * 16);
#pragma unroll
    for (int cp = 0; cp < COPIES; ++cp)
      tsum[cp] += (tg[cp].x + tg[cp].y) + (tg[cp].z + tg[cp].w);
    float4 cx[IH];
#pragma unroll
    for (int ii = 0; ii < IH; ++ii) {
      const int f4 = (kc0 + c4) ^ rsw[ii];
      cx[ii] = *reinterpret_cast<const float4*>(&lds[rbase[ii] + (f4 << 2)]);
    }
#pragma unroll
    for (int ii = 0; ii < IH; ++ii)
#pragma unroll
      for (int cp = 0; cp < COPIES; ++cp) {
        acc[ii][cp] = fmaf(cx[ii].x, tg[cp].x, acc[ii][cp]);
        acc[ii][cp] = fmaf(cx[ii].y, tg[cp].y, acc[ii][cp]);
        acc[ii][cp] = fmaf(cx[ii].z, tg[cp].z, acc[ii][cp]);
        acc[ii][cp] = fmaf(cx[ii].w, tg[cp].w, acc[ii][cp]);
      }
  }

  // Combine the two k-halves (partner lane = xor 1)
#pragma unroll
  for (int ii = 0; ii < IH; ++ii)
#pragma unroll
    for (int cp = 0; cp < COPIES; ++cp) acc[ii][cp] += __shfl_xor(acc[ii][cp], 1);
#pragma unroll
  for (int cp = 0; cp < COPIES; ++cp) tsum[cp] += __shfl_xor(tsum[cp], 1);

  // Per-thread: logsumexp over this i-half's 6 steps
  float contrib = 0.f;
#pragma unroll
  for (int ii = 0; ii < IH; ++ii) {
    const int i = ih * IH + ii;
    if (i <= tp) {
      const float w = Ws[i], bbias = bs[i];
      float lg[COPIES];
      float m = -INFINITY;
#pragma unroll
      for (int cp = 0; cp < COPIES; ++cp) {
        lg[cp] = fmaf(w, acc[ii][cp], bbias * tsum[cp]);
        m = fmaxf(m, lg[cp]);
      }
      float s = 0.f;
#pragma unroll
      for (int cp = 0; cp < COPIES; ++cp) s += expf(lg[cp] - m);
      contrib += m + logf(s) - lg[0];
    }
  }
  contrib += __shfl_xor(contrib, 2);  // combine the two i-halves
  if ((tid & 3) == 0) partials[(size_t)b * TT + tp] = contrib;
}

// ---------------- Kernel 3: deterministic reduction of 32768 partials (double accum)
__global__ __launch_bounds__(256) void reduce_kernel(const float* __restrict__ partials,
                                                     float* __restrict__ out) {
  __shared__ double sred[256];
  double acc = 0.0;
  for (int idx = threadIdx.x; idx < MM; idx += 256) acc += (double)partials[idx];
  sred[threadIdx.x] = acc;
  __syncthreads();
  for (int s = 128; s > 0; s >>= 1) {
    if (threadIdx.x < s) sred[threadIdx.x] += sred[threadIdx.x + s];
    __syncthreads();
  }
  if (threadIdx.x == 0) out[0] = (float)sred[0];
}

extern "C" void kernel_launch(void* const* d_in, const int* in_sizes, int n_in,
                              void* d_out, int out_size, void* d_ws, size_t ws_size,
                              hipStream_t stream) {
  const float* true_latent = (const float*)d_in[0];     // [BB,TT,FF]
  const float* context_latent = (const float*)d_in[1];  // [BB,TT,CC]
  const float* Wl = (const float*)d_in[2];              // [FF,CC]
  const float* bl = (const float*)d_in[3];              // [CC]
  const float* Ws = (const float*)d_in[4];              // [NSTEPS]
  const float* bs = (const float*)d_in[5];              // [NSTEPS]
  const int* negs = (const int*)d_in[6];                // [BB,NEG,TT]

  float* tl = (float*)d_ws;                                                    // 32 MB
  float* partials = (float*)((char*)d_ws + (size_t)MM * CC * sizeof(float));   // 128 KB

  dim3 g1(MM / 128, CC / 128);
  proj_gemm_kernel<<<g1, 256, 0, stream>>>(true_latent, Wl, bl, tl);
  cpc_loss_kernel<<<BB * (TT / TP), 256, 0, stream>>>(context_latent, tl, negs, Ws, bs, partials);
  reduce_kernel<<<1, 256, 0, stream>>>(partials, (float*)d_out);
}

// Round 8
// 351.433 us; speedup vs baseline: 1.3398x; 1.3398x over previous
//
#include <hip/hip_runtime.h>
#include <math.h>

#define BB 16
#define TT 2048
#define FF 512
#define CC 256
#define NEG 10
#define NSTEPS 12
#define COPIES 11
#define MM (BB * TT)

// ---------------- Kernel 1: tl = true_latent @ Wl + bl  (f32 GEMM 32768x512x256)
// 128x128 tile, 256 threads, 8x8 outputs/thread, BK=16, k-major A, reg prefetch.
__global__ __launch_bounds__(256) void proj_gemm_kernel(
    const float* __restrict__ A,     // [MM, FF] row-major
    const float* __restrict__ W,     // [FF, CC] row-major
    const float* __restrict__ bias,  // [CC]
    float* __restrict__ Out) {       // [MM, CC]
  __shared__ __align__(16) float As[16][132];
  __shared__ __align__(16) float Bs[16][128];
  const int tid = threadIdx.x;
  const int bm = blockIdx.x * 128;
  const int bn = blockIdx.y * 128;
  const int tx = tid & 15;
  const int ty = tid >> 4;
  const int am = tid >> 1;
  const int ak = (tid & 1) * 8;
  const int bk = tid >> 5;
  const int bc = (tid & 31) * 4;
  float acc[8][8] = {};

  const float* Ap = &A[(size_t)(bm + am) * FF + ak];
  const float* Bp = &W[(size_t)bk * CC + bn + bc];
  float4 pa0 = *reinterpret_cast<const float4*>(Ap);
  float4 pa1 = *reinterpret_cast<const float4*>(Ap + 4);
  float4 pb0 = *reinterpret_cast<const float4*>(Bp);
  float4 pb1 = *reinterpret_cast<const float4*>(Bp + 8 * CC);

  for (int kt = 0; kt < FF / 16; ++kt) {
    __syncthreads();
    As[ak + 0][am] = pa0.x; As[ak + 1][am] = pa0.y;
    As[ak + 2][am] = pa0.z; As[ak + 3][am] = pa0.w;
    As[ak + 4][am] = pa1.x; As[ak + 5][am] = pa1.y;
    As[ak + 6][am] = pa1.z; As[ak + 7][am] = pa1.w;
    *reinterpret_cast<float4*>(&Bs[bk][bc]) = pb0;
    *reinterpret_cast<float4*>(&Bs[bk + 8][bc]) = pb1;
    __syncthreads();
    if (kt + 1 < FF / 16) {
      const float* Apn = Ap + (kt + 1) * 16;
      const float* Bpn = Bp + (size_t)(kt + 1) * 16 * CC;
      pa0 = *reinterpret_cast<const float4*>(Apn);
      pa1 = *reinterpret_cast<const float4*>(Apn + 4);
      pb0 = *reinterpret_cast<const float4*>(Bpn);
      pb1 = *reinterpret_cast<const float4*>(Bpn + 8 * CC);
    }
#pragma unroll
    for (int kk = 0; kk < 16; ++kk) {
      const float4 a0 = *reinterpret_cast<const float4*>(&As[kk][ty * 8]);
      const float4 a1 = *reinterpret_cast<const float4*>(&As[kk][ty * 8 + 4]);
      const float4 b0 = *reinterpret_cast<const float4*>(&Bs[kk][tx * 8]);
      const float4 b1 = *reinterpret_cast<const float4*>(&Bs[kk][tx * 8 + 4]);
      const float av[8] = {a0.x, a0.y, a0.z, a0.w, a1.x, a1.y, a1.z, a1.w};
      const float bv[8] = {b0.x, b0.y, b0.z, b0.w, b1.x, b1.y, b1.z, b1.w};
#pragma unroll
      for (int i = 0; i < 8; ++i)
#pragma unroll
        for (int j = 0; j < 8; ++j) acc[i][j] = fmaf(av[i], bv[j], acc[i][j]);
    }
  }
  float bz[8];
#pragma unroll
  for (int j = 0; j < 8; ++j) bz[j] = bias[bn + tx * 8 + j];
#pragma unroll
  for (int i = 0; i < 8; ++i) {
    float4 o0, o1;
    o0.x = acc[i][0] + bz[0]; o0.y = acc[i][1] + bz[1];
    o0.z = acc[i][2] + bz[2]; o0.w = acc[i][3] + bz[3];
    o1.x = acc[i][4] + bz[4]; o1.y = acc[i][5] + bz[5];
    o1.z = acc[i][6] + bz[6]; o1.w = acc[i][7] + bz[7];
    float* orow = &Out[(size_t)(bm + ty * 8 + i) * CC + bn + tx * 8];
    *reinterpret_cast<float4*>(orow) = o0;
    *reinterpret_cast<float4*>(orow + 4) = o1;
  }
}

// ---------------- Kernel 2: per-(b, 32 consecutive t') block, XCD-pinned per b.
// 8 lanes per t': kg (k-half, 128 floats) x ch (copy-quarter, 3 copies). No duplicated
// gather bytes (12 KB/t'). acc[12][3] in regs (~100 VGPR). ctx window in LDS
// (XOR-swizzled). LSE via LDS scatter of the 12x11 dot matrix (no runtime reg indexing).
#define TP 32
#define NROWS (TP + COPIES)  // 43 ctx rows: [tp0-11, tp0+31]
#define NCP 3
__global__ __launch_bounds__(256, 3) void cpc_loss_kernel(
    const float* __restrict__ ctx,  // [BB, TT, CC]
    const float* __restrict__ tl,   // [BB, TT, CC]
    const int* __restrict__ negs,   // [BB, NEG, TT]
    const float* __restrict__ Ws,   // [NSTEPS]
    const float* __restrict__ bs,   // [NSTEPS]
    float* __restrict__ partials) { // [gridDim.x]
  __shared__ __align__(16) float lds[NROWS * CC];  // 43 KB; reused for dot matrix + reduce
  const int tid = threadIdx.x;
  const int tloc = tid >> 3;       // 0..31: local t'
  const int ch = (tid >> 1) & 3;   // copy-quarter
  const int kg = tid & 1;          // k-half
  // XCD pinning: HW assigns XCD = blockIdx % 8 (round-robin); decode so b%8 == wg%8.
  const int wg = blockIdx.x;
  const int b = (wg & 7) | (((wg >> 3) & 1) << 3);
  const int chunk = wg >> 4;       // 0..63
  const int tp0 = chunk * TP;
  const int tp = tp0 + tloc;

  // Stage ctx window; float4-index XOR-swizzled by (row&7)
  for (int idx = tid; idx < NROWS * (CC / 4); idx += 256) {
    const int r = idx >> 6;
    const int c4 = idx & 63;
    const int t = tp0 - COPIES + r;
    float4 v = make_float4(0.f, 0.f, 0.f, 0.f);
    if (t >= 0) v = *reinterpret_cast<const float4*>(&ctx[((size_t)b * TT + t) * CC + c4 * 4]);
    *reinterpret_cast<float4*>(&lds[r * CC + ((c4 ^ (r & 7)) << 2)]) = v;
  }

  // Gather byte offsets for this thread's 3 copies x k-half (clamped dummy for ch=3,j=2)
  unsigned off[NCP];
#pragma unroll
  for (int j = 0; j < NCP; ++j) {
    int cp = ch * 3 + j;
    if (cp > 10) cp = 10;
    const int u = (cp == 0) ? tp : negs[((size_t)b * NEG + (cp - 1)) * TT + tp];
    off[j] = (unsigned)(((size_t)b * TT + u) * CC + kg * 128) * 4u;
  }
  const char* tlb = (const char*)tl;

  int rowb[NSTEPS], rsw[NSTEPS];
#pragma unroll
  for (int i = 0; i < NSTEPS; ++i) {
    const int r = tloc + COPIES - i;  // ctx row for step i: t = tp - i
    rowb[i] = r * CC;
    rsw[i] = r & 7;
  }

  float acc[NSTEPS][NCP] = {};
  float tsum[NCP] = {};
  __syncthreads();

  for (int c4 = 0; c4 < 32; ++c4) {  // this thread's 128-float k-half
    float4 tg[NCP];
#pragma unroll
    for (int j = 0; j < NCP; ++j)
      tg[j] = *reinterpret_cast<const float4*>(tlb + off[j] + c4 * 16);
#pragma unroll
    for (int j = 0; j < NCP; ++j)
      tsum[j] += (tg[j].x + tg[j].y) + (tg[j].z + tg[j].w);
    const int kc = kg * 32 + c4;
#pragma unroll
    for (int i = 0; i < NSTEPS; ++i) {
      const float4 cx = *reinterpret_cast<const float4*>(&lds[rowb[i] + ((kc ^ rsw[i]) << 2)]);
#pragma unroll
      for (int j = 0; j < NCP; ++j) {
        acc[i][j] = fmaf(cx.x, tg[j].x, acc[i][j]);
        acc[i][j] = fmaf(cx.y, tg[j].y, acc[i][j]);
        acc[i][j] = fmaf(cx.z, tg[j].z, acc[i][j]);
        acc[i][j] = fmaf(cx.w, tg[j].w, acc[i][j]);
      }
    }
  }

  // Combine k-halves (partner = lane^1)
#pragma unroll
  for (int i = 0; i < NSTEPS; ++i)
#pragma unroll
    for (int j = 0; j < NCP; ++j) acc[i][j] += __shfl_xor(acc[i][j], 1);
#pragma unroll
  for (int j = 0; j < NCP; ++j) tsum[j] += __shfl_xor(tsum[j], 1);

  __syncthreads();  // all ctx reads done; reuse lds for dot matrix
  float* sd = lds;                       // [32*12][13]: dot(t',i,cp), stride 13 (conflict-free)
  float* ts = lds + TP * NSTEPS * 13;    // [32][13]: target row sums
  if (kg == 0) {
#pragma unroll
    for (int j = 0; j < NCP; ++j) {
      const int cp = ch * 3 + j;
      if (cp <= 10) {
        ts[tloc * 13 + cp] = tsum[j];
#pragma unroll
        for (int i = 0; i < NSTEPS; ++i) sd[(tloc * NSTEPS + i) * 13 + cp] = acc[i][j];
      }
    }
  }
  __syncthreads();

  // LSE tasks: 384 = 32 t' x 12 steps
  float contrib = 0.f;
  for (int task = tid; task < TP * NSTEPS; task += 256) {
    const int tt = task / NSTEPS;
    const int i = task - tt * NSTEPS;
    if (i <= tp0 + tt) {
      const float w = Ws[i], bbias = bs[i];
      const float* drow = &sd[task * 13];
      const float* trow = &ts[tt * 13];
      float lg[COPIES];
      float m = -INFINITY;
#pragma unroll
      for (int cp = 0; cp < COPIES; ++cp) {
        lg[cp] = fmaf(w, drow[cp], bbias * trow[cp]);
        m = fmaxf(m, lg[cp]);
      }
      float s = 0.f;
#pragma unroll
      for (int cp = 0; cp < COPIES; ++cp) s += expf(lg[cp] - m);
      contrib += m + logf(s) - lg[0];
    }
  }

  // Block reduction
  __syncthreads();
  lds[tid] = contrib;
  __syncthreads();
  for (int s = 128; s > 0; s >>= 1) {
    if (tid < s) lds[tid] += lds[tid + s];
    __syncthreads();
  }
  if (tid == 0) partials[wg] = lds[0];
}

#define NBLK (BB * (TT / TP))  // 1024
// ---------------- Kernel 3: deterministic reduction of block partials (double accum)
__global__ __launch_bounds__(256) void reduce_kernel(const float* __restrict__ partials,
                                                     float* __restrict__ out) {
  __shared__ double sred[256];
  double acc = 0.0;
  for (int idx = threadIdx.x; idx < NBLK; idx += 256) acc += (double)partials[idx];
  sred[threadIdx.x] = acc;
  __syncthreads();
  for (int s = 128; s > 0; s >>= 1) {
    if (threadIdx.x < s) sred[threadIdx.x] += sred[threadIdx.x + s];
    __syncthreads();
  }
  if (threadIdx.x == 0) out[0] = (float)sred[0];
}

extern "C" void kernel_launch(void* const* d_in, const int* in_sizes, int n_in,
                              void* d_out, int out_size, void* d_ws, size_t ws_size,
                              hipStream_t stream) {
  const float* true_latent = (const float*)d_in[0];     // [BB,TT,FF]
  const float* context_latent = (const float*)d_in[1];  // [BB,TT,CC]
  const float* Wl = (const float*)d_in[2];              // [FF,CC]
  const float* bl = (const float*)d_in[3];              // [CC]
  const float* Ws = (const float*)d_in[4];              // [NSTEPS]
  const float* bs = (const float*)d_in[5];              // [NSTEPS]
  const int* negs = (const int*)d_in[6];                // [BB,NEG,TT]

  float* tl = (float*)d_ws;                                                    // 32 MB
  float* partials = (float*)((char*)d_ws + (size_t)MM * CC * sizeof(float));   // 4 KB

  dim3 g1(MM / 128, CC / 128);
  proj_gemm_kernel<<<g1, 256, 0, stream>>>(true_latent, Wl, bl, tl);
  cpc_loss_kernel<<<NBLK, 256, 0, stream>>>(context_latent, tl, negs, Ws, bs, partials);
  reduce_kernel<<<1, 256, 0, stream>>>(partials, (float*)d_out);
}

// Round 10
// 273.018 us; speedup vs baseline: 1.7246x; 1.2872x over previous
//
#include <hip/hip_runtime.h>
#include <math.h>

#define BB 16
#define TT 2048
#define FF 512
#define CC 256
#define NEG 10
#define NSTEPS 12
#define COPIES 11
#define MM (BB * TT)

// ---------------- Kernel 1: tl = true_latent @ Wl + bl  (f32 GEMM 32768x512x256)
// 128x128 tile, 256 threads, 8x8 outputs/thread, BK=16, k-major A, reg prefetch.
__global__ __launch_bounds__(256) void proj_gemm_kernel(
    const float* __restrict__ A,     // [MM, FF] row-major
    const float* __restrict__ W,     // [FF, CC] row-major
    const float* __restrict__ bias,  // [CC]
    float* __restrict__ Out) {       // [MM, CC]
  __shared__ __align__(16) float As[16][132];
  __shared__ __align__(16) float Bs[16][128];
  const int tid = threadIdx.x;
  const int bm = blockIdx.x * 128;
  const int bn = blockIdx.y * 128;
  const int tx = tid & 15;
  const int ty = tid >> 4;
  const int am = tid >> 1;
  const int ak = (tid & 1) * 8;
  const int bk = tid >> 5;
  const int bc = (tid & 31) * 4;
  float acc[8][8] = {};

  const float* Ap = &A[(size_t)(bm + am) * FF + ak];
  const float* Bp = &W[(size_t)bk * CC + bn + bc];
  float4 pa0 = *reinterpret_cast<const float4*>(Ap);
  float4 pa1 = *reinterpret_cast<const float4*>(Ap + 4);
  float4 pb0 = *reinterpret_cast<const float4*>(Bp);
  float4 pb1 = *reinterpret_cast<const float4*>(Bp + 8 * CC);

  for (int kt = 0; kt < FF / 16; ++kt) {
    __syncthreads();
    As[ak + 0][am] = pa0.x; As[ak + 1][am] = pa0.y;
    As[ak + 2][am] = pa0.z; As[ak + 3][am] = pa0.w;
    As[ak + 4][am] = pa1.x; As[ak + 5][am] = pa1.y;
    As[ak + 6][am] = pa1.z; As[ak + 7][am] = pa1.w;
    *reinterpret_cast<float4*>(&Bs[bk][bc]) = pb0;
    *reinterpret_cast<float4*>(&Bs[bk + 8][bc]) = pb1;
    __syncthreads();
    if (kt + 1 < FF / 16) {
      const float* Apn = Ap + (kt + 1) * 16;
      const float* Bpn = Bp + (size_t)(kt + 1) * 16 * CC;
      pa0 = *reinterpret_cast<const float4*>(Apn);
      pa1 = *reinterpret_cast<const float4*>(Apn + 4);
      pb0 = *reinterpret_cast<const float4*>(Bpn);
      pb1 = *reinterpret_cast<const float4*>(Bpn + 8 * CC);
    }
#pragma unroll
    for (int kk = 0; kk < 16; ++kk) {
      const float4 a0 = *reinterpret_cast<const float4*>(&As[kk][ty * 8]);
      const float4 a1 = *reinterpret_cast<const float4*>(&As[kk][ty * 8 + 4]);
      const float4 b0 = *reinterpret_cast<const float4*>(&Bs[kk][tx * 8]);
      const float4 b1 = *reinterpret_cast<const float4*>(&Bs[kk][tx * 8 + 4]);
      const float av[8] = {a0.x, a0.y, a0.z, a0.w, a1.x, a1.y, a1.z, a1.w};
      const float bv[8] = {b0.x, b0.y, b0.z, b0.w, b1.x, b1.y, b1.z, b1.w};
#pragma unroll
      for (int i = 0; i < 8; ++i)
#pragma unroll
        for (int j = 0; j < 8; ++j) acc[i][j] = fmaf(av[i], bv[j], acc[i][j]);
    }
  }
  float bz[8];
#pragma unroll
  for (int j = 0; j < 8; ++j) bz[j] = bias[bn + tx * 8 + j];
#pragma unroll
  for (int i = 0; i < 8; ++i) {
    float4 o0, o1;
    o0.x = acc[i][0] + bz[0]; o0.y = acc[i][1] + bz[1];
    o0.z = acc[i][2] + bz[2]; o0.w = acc[i][3] + bz[3];
    o1.x = acc[i][4] + bz[4]; o1.y = acc[i][5] + bz[5];
    o1.z = acc[i][6] + bz[6]; o1.w = acc[i][7] + bz[7];
    float* orow = &Out[(size_t)(bm + ty * 8 + i) * CC + bn + tx * 8];
    *reinterpret_cast<float4*>(orow) = o0;
    *reinterpret_cast<float4*>(orow + 4) = o1;
  }
}

// ---------------- Kernel 2: per-(b, 16 t') block, XCD-pinned per b.
// 16 lanes per t': kg (k-quarter, interleaved float4 stride 4) x ch (copy-quarter, 3
// copies). Gather software-pipelined (load c4+1 while computing c4). acc[12][3] regs.
// ctx window in LDS (XOR-swizzled). LSE via LDS scatter of the dot matrix.
#define TP 16
#define NROWS (TP + COPIES)  // 27 ctx rows: [tp0-11, tp0+15]
#define NCP 3
__global__ __launch_bounds__(256, 4) void cpc_loss_kernel(
    const float* __restrict__ ctx,  // [BB, TT, CC]
    const float* __restrict__ tl,   // [BB, TT, CC]
    const int* __restrict__ negs,   // [BB, NEG, TT]
    const float* __restrict__ Ws,   // [NSTEPS]
    const float* __restrict__ bs,   // [NSTEPS]
    float* __restrict__ partials) { // [gridDim.x]
  __shared__ __align__(16) float lds[NROWS * CC];  // 27 KB; reused for dot matrix + reduce
  const int tid = threadIdx.x;
  const int tloc = tid >> 4;       // 0..15: local t'
  const int ch = (tid >> 2) & 3;   // copy-quarter
  const int kg = tid & 3;          // k-quarter (interleaved)
  // XCD pinning: HW assigns XCD = blockIdx % 8 (round-robin); decode so b%8 == wg%8.
  const int wg = blockIdx.x;
  const int b = (wg & 7) | (((wg >> 3) & 1) << 3);
  const int chunk = wg >> 4;       // 0..127
  const int tp0 = chunk * TP;
  const int tp = tp0 + tloc;

  // Stage ctx window; float4-index XOR-swizzled by (row&7)
  for (int idx = tid; idx < NROWS * (CC / 4); idx += 256) {
    const int r = idx >> 6;
    const int c4 = idx & 63;
    const int t = tp0 - COPIES + r;
    float4 v = make_float4(0.f, 0.f, 0.f, 0.f);
    if (t >= 0) v = *reinterpret_cast<const float4*>(&ctx[((size_t)b * TT + t) * CC + c4 * 4]);
    *reinterpret_cast<float4*>(&lds[r * CC + ((c4 ^ (r & 7)) << 2)]) = v;
  }

  // Gather row-base byte offsets for this thread's 3 copies (clamped dummy ch=3,j=2)
  unsigned off[NCP];
#pragma unroll
  for (int j = 0; j < NCP; ++j) {
    int cp = ch * 3 + j;
    if (cp > 10) cp = 10;
    const int u = (cp == 0) ? tp : negs[((size_t)b * NEG + (cp - 1)) * TT + tp];
    off[j] = (unsigned)(((size_t)b * TT + u) * CC) * 4u;
  }
  const char* tlb = (const char*)tl;

  int rowb[NSTEPS], rsw[NSTEPS];
#pragma unroll
  for (int i = 0; i < NSTEPS; ++i) {
    const int r = tloc + COPIES - i;  // ctx row for step i: t = tp - i
    rowb[i] = r * CC;
    rsw[i] = r & 7;
  }

  float acc[NSTEPS][NCP] = {};
  float tsum[NCP] = {};
  __syncthreads();

  // Software-pipelined gather: this thread's 16 float4s of each copy row are
  // e4 = c4*4 + kg (interleaved so kg spreads LDS bank groups).
  float4 tg[NCP];
#pragma unroll
  for (int j = 0; j < NCP; ++j)
    tg[j] = *reinterpret_cast<const float4*>(tlb + off[j] + (unsigned)(kg << 4));
#pragma unroll
  for (int c4 = 0; c4 < 16; ++c4) {
    float4 tgn[NCP];
    if (c4 < 15) {
      const unsigned e4n = (unsigned)((((c4 + 1) << 2) | kg) << 4);
#pragma unroll
      for (int j = 0; j < NCP; ++j)
        tgn[j] = *reinterpret_cast<const float4*>(tlb + off[j] + e4n);
    }
#pragma unroll
    for (int j = 0; j < NCP; ++j)
      tsum[j] += (tg[j].x + tg[j].y) + (tg[j].z + tg[j].w);
    const int e4 = (c4 << 2) | kg;
#pragma unroll
    for (int i = 0; i < NSTEPS; ++i) {
      const float4 cx = *reinterpret_cast<const float4*>(&lds[rowb[i] + ((e4 ^ rsw[i]) << 2)]);
#pragma unroll
      for (int j = 0; j < NCP; ++j) {
        acc[i][j] = fmaf(cx.x, tg[j].x, acc[i][j]);
        acc[i][j] = fmaf(cx.y, tg[j].y, acc[i][j]);
        acc[i][j] = fmaf(cx.z, tg[j].z, acc[i][j]);
        acc[i][j] = fmaf(cx.w, tg[j].w, acc[i][j]);
      }
    }
    if (c4 < 15) {
#pragma unroll
      for (int j = 0; j < NCP; ++j) tg[j] = tgn[j];
    }
  }

  // Combine the 4 k-quarters (lanes differ in bits 0-1)
#pragma unroll
  for (int i = 0; i < NSTEPS; ++i)
#pragma unroll
    for (int j = 0; j < NCP; ++j) {
      acc[i][j] += __shfl_xor(acc[i][j], 1);
      acc[i][j] += __shfl_xor(acc[i][j], 2);
    }
#pragma unroll
  for (int j = 0; j < NCP; ++j) {
    tsum[j] += __shfl_xor(tsum[j], 1);
    tsum[j] += __shfl_xor(tsum[j], 2);
  }

  __syncthreads();  // all ctx reads done; reuse lds for dot matrix
  float* sd = lds;                       // [16*12][13]: dot(t',i,cp), stride 13
  float* ts = lds + TP * NSTEPS * 13;    // [16][13]: target row sums
  if (kg == 0) {
#pragma unroll
    for (int j = 0; j < NCP; ++j) {
      const int cp = ch * 3 + j;
      if (cp <= 10) {
        ts[tloc * 13 + cp] = tsum[j];
#pragma unroll
        for (int i = 0; i < NSTEPS; ++i) sd[(tloc * NSTEPS + i) * 13 + cp] = acc[i][j];
      }
    }
  }
  __syncthreads();

  // LSE tasks: 192 = 16 t' x 12 steps
  float contrib = 0.f;
  if (tid < TP * NSTEPS) {
    const int tt = tid / NSTEPS;
    const int i = tid - tt * NSTEPS;
    if (i <= tp0 + tt) {
      const float w = Ws[i], bbias = bs[i];
      const float* drow = &sd[tid * 13];
      const float* trow = &ts[tt * 13];
      float lg[COPIES];
      float m = -INFINITY;
#pragma unroll
      for (int cp = 0; cp < COPIES; ++cp) {
        lg[cp] = fmaf(w, drow[cp], bbias * trow[cp]);
        m = fmaxf(m, lg[cp]);
      }
      float s = 0.f;
#pragma unroll
      for (int cp = 0; cp < COPIES; ++cp) s += expf(lg[cp] - m);
      contrib = m + logf(s) - lg[0];
    }
  }

  // Block reduction
  __syncthreads();
  lds[tid] = contrib;
  __syncthreads();
  for (int s = 128; s > 0; s >>= 1) {
    if (tid < s) lds[tid] += lds[tid + s];
    __syncthreads();
  }
  if (tid == 0) partials[wg] = lds[0];
}

#define NBLK (BB * (TT / TP))  // 2048
// ---------------- Kernel 3: deterministic reduction of block partials (double accum)
__global__ __launch_bounds__(256) void reduce_kernel(const float* __restrict__ partials,
                                                     float* __restrict__ out) {
  __shared__ double sred[256];
  double acc = 0.0;
  for (int idx = threadIdx.x; idx < NBLK; idx += 256) acc += (double)partials[idx];
  sred[threadIdx.x] = acc;
  __syncthreads();
  for (int s = 128; s > 0; s >>= 1) {
    if (threadIdx.x < s) sred[threadIdx.x] += sred[threadIdx.x + s];
    __syncthreads();
  }
  if (threadIdx.x == 0) out[0] = (float)sred[0];
}

extern "C" void kernel_launch(void* const* d_in, const int* in_sizes, int n_in,
                              void* d_out, int out_size, void* d_ws, size_t ws_size,
                              hipStream_t stream) {
  const float* true_latent = (const float*)d_in[0];     // [BB,TT,FF]
  const float* context_latent = (const float*)d_in[1];  // [BB,TT,CC]
  const float* Wl = (const float*)d_in[2];              // [FF,CC]
  const float* bl = (const float*)d_in[3];              // [CC]
  const float* Ws = (const float*)d_in[4];              // [NSTEPS]
  const float* bs = (const float*)d_in[5];              // [NSTEPS]
  const int* negs = (const int*)d_in[6];                // [BB,NEG,TT]

  float* tl = (float*)d_ws;                                                    // 32 MB
  float* partials = (float*)((char*)d_ws + (size_t)MM * CC * sizeof(float));   // 8 KB

  dim3 g1(MM / 128, CC / 128);
  proj_gemm_kernel<<<g1, 256, 0, stream>>>(true_latent, Wl, bl, tl);
  cpc_loss_kernel<<<NBLK, 256, 0, stream>>>(context_latent, tl, negs, Ws, bs, partials);
  reduce_kernel<<<1, 256, 0, stream>>>(partials, (float*)d_out);
}

// Round 13
// 264.192 us; speedup vs baseline: 1.7822x; 1.0334x over previous
//
#include <hip/hip_runtime.h>
#include <math.h>

#define BB 16
#define TT 2048
#define FF 512
#define CC 256
#define NEG 10
#define NSTEPS 12
#define COPIES 11
#define MM (BB * TT)

// ---------------- Kernel 1: tl = true_latent @ Wl + bl  (f32 GEMM 32768x512x256)
// 128x64 tile, 256 threads, 8x4 outputs/thread (split-M: rows ty*4 and 64+ty*4 ->
// LDS read stride 4 floats = 2-way banks, free). Double-buffered LDS, 1 barrier/tile.
#define GA_STRIDE 132  // A LDS row stride (k-major)
#define GB_STRIDE 68   // B LDS row stride
__global__ __launch_bounds__(256, 4) void proj_gemm_kernel(
    const float* __restrict__ A,     // [MM, FF] row-major
    const float* __restrict__ W,     // [FF, CC] row-major
    const float* __restrict__ bias,  // [CC]
    float* __restrict__ Out) {       // [MM, CC]
  __shared__ __align__(16) float As[2][16 * GA_STRIDE];  // k-major: [kk][row 0..127]
  __shared__ __align__(16) float Bs[2][16 * GB_STRIDE];  // [kk][col 0..63]
  const int tid = threadIdx.x;
  const int bm = blockIdx.x * 128;
  const int bn = blockIdx.y * 64;
  const int tx = tid & 15;   // col group: cols tx*4..tx*4+3
  const int ty = tid >> 4;   // row group: rows ty*4 and 64+ty*4
  // A staging: thread loads A[am][k0+ak .. ak+7] (2 float4)
  const int am = tid >> 1;
  const int ak = (tid & 1) * 8;
  // B staging: thread loads W[k0+brow][bn + bc4*4 ..] (1 float4)
  const int brow = tid >> 4;
  const int bc4 = tid & 15;
  float acc[8][4] = {};

  const float* Ap = &A[(size_t)(bm + am) * FF + ak];
  const float* Bp = &W[(size_t)brow * CC + bn + bc4 * 4];

  // Prologue: load tile 0, write buf 0
  float4 pa0 = *reinterpret_cast<const float4*>(Ap);
  float4 pa1 = *reinterpret_cast<const float4*>(Ap + 4);
  float4 pb0 = *reinterpret_cast<const float4*>(Bp);
  {
    float* a = As[0];
    a[(ak + 0) * GA_STRIDE + am] = pa0.x; a[(ak + 1) * GA_STRIDE + am] = pa0.y;
    a[(ak + 2) * GA_STRIDE + am] = pa0.z; a[(ak + 3) * GA_STRIDE + am] = pa0.w;
    a[(ak + 4) * GA_STRIDE + am] = pa1.x; a[(ak + 5) * GA_STRIDE + am] = pa1.y;
    a[(ak + 6) * GA_STRIDE + am] = pa1.z; a[(ak + 7) * GA_STRIDE + am] = pa1.w;
    *reinterpret_cast<float4*>(&Bs[0][brow * GB_STRIDE + bc4 * 4]) = pb0;
  }
  __syncthreads();

  const int NT = FF / 16;  // 32 k-tiles
  for (int kt = 0; kt < NT; ++kt) {
    const int cur = kt & 1;
    if (kt + 1 < NT) {  // issue next tile's global loads; latency hides under compute
      const float* Apn = Ap + (kt + 1) * 16;
      const float* Bpn = Bp + (size_t)(kt + 1) * 16 * CC;
      pa0 = *reinterpret_cast<const float4*>(Apn);
      pa1 = *reinterpret_cast<const float4*>(Apn + 4);
      pb0 = *reinterpret_cast<const float4*>(Bpn);
    }
    const float* a = As[cur];
    const float* bsh = Bs[cur];
#pragma unroll
    for (int kk = 0; kk < 16; ++kk) {
      const float4 a0 = *reinterpret_cast<const float4*>(&a[kk * GA_STRIDE + ty * 4]);
      const float4 a1 = *reinterpret_cast<const float4*>(&a[kk * GA_STRIDE + 64 + ty * 4]);
      const float4 b0 = *reinterpret_cast<const float4*>(&bsh[kk * GB_STRIDE + tx * 4]);
      const float av[8] = {a0.x, a0.y, a0.z, a0.w, a1.x, a1.y, a1.z, a1.w};
      const float bv[4] = {b0.x, b0.y, b0.z, b0.w};
#pragma unroll
      for (int i = 0; i < 8; ++i)
#pragma unroll
        for (int j = 0; j < 4; ++j) acc[i][j] = fmaf(av[i], bv[j], acc[i][j]);
    }
    if (kt + 1 < NT) {  // write next tile to the other buffer, single barrier
      float* an = As[cur ^ 1];
      an[(ak + 0) * GA_STRIDE + am] = pa0.x; an[(ak + 1) * GA_STRIDE + am] = pa0.y;
      an[(ak + 2) * GA_STRIDE + am] = pa0.z; an[(ak + 3) * GA_STRIDE + am] = pa0.w;
      an[(ak + 4) * GA_STRIDE + am] = pa1.x; an[(ak + 5) * GA_STRIDE + am] = pa1.y;
      an[(ak + 6) * GA_STRIDE + am] = pa1.z; an[(ak + 7) * GA_STRIDE + am] = pa1.w;
      *reinterpret_cast<float4*>(&Bs[cur ^ 1][brow * GB_STRIDE + bc4 * 4]) = pb0;
      __syncthreads();
    }
  }

  const float4 b4 = *reinterpret_cast<const float4*>(&bias[bn + tx * 4]);
  const float bz[4] = {b4.x, b4.y, b4.z, b4.w};
#pragma unroll
  for (int h = 0; h < 2; ++h)
#pragma unroll
    for (int i = 0; i < 4; ++i) {
      float4 o;
      o.x = acc[h * 4 + i][0] + bz[0];
      o.y = acc[h * 4 + i][1] + bz[1];
      o.z = acc[h * 4 + i][2] + bz[2];
      o.w = acc[h * 4 + i][3] + bz[3];
      *reinterpret_cast<float4*>(&Out[(size_t)(bm + h * 64 + ty * 4 + i) * CC + bn + tx * 4]) = o;
    }
}

// ---------------- Kernel 2: per-(b, 16 t') block, XCD-pinned per b. (unchanged from R9)
#define TP 16
#define NROWS (TP + COPIES)  // 27 ctx rows: [tp0-11, tp0+15]
#define NCP 3
__global__ __launch_bounds__(256, 4) void cpc_loss_kernel(
    const float* __restrict__ ctx,  // [BB, TT, CC]
    const float* __restrict__ tl,   // [BB, TT, CC]
    const int* __restrict__ negs,   // [BB, NEG, TT]
    const float* __restrict__ Ws,   // [NSTEPS]
    const float* __restrict__ bs,   // [NSTEPS]
    float* __restrict__ partials) { // [gridDim.x]
  __shared__ __align__(16) float lds[NROWS * CC];  // 27 KB; reused for dot matrix + reduce
  const int tid = threadIdx.x;
  const int tloc = tid >> 4;       // 0..15: local t'
  const int ch = (tid >> 2) & 3;   // copy-quarter
  const int kg = tid & 3;          // k-quarter (interleaved)
  const int wg = blockIdx.x;
  const int b = (wg & 7) | (((wg >> 3) & 1) << 3);
  const int chunk = wg >> 4;       // 0..127
  const int tp0 = chunk * TP;
  const int tp = tp0 + tloc;

  for (int idx = tid; idx < NROWS * (CC / 4); idx += 256) {
    const int r = idx >> 6;
    const int c4 = idx & 63;
    const int t = tp0 - COPIES + r;
    float4 v = make_float4(0.f, 0.f, 0.f, 0.f);
    if (t >= 0) v = *reinterpret_cast<const float4*>(&ctx[((size_t)b * TT + t) * CC + c4 * 4]);
    *reinterpret_cast<float4*>(&lds[r * CC + ((c4 ^ (r & 7)) << 2)]) = v;
  }

  unsigned off[NCP];
#pragma unroll
  for (int j = 0; j < NCP; ++j) {
    int cp = ch * 3 + j;
    if (cp > 10) cp = 10;
    const int u = (cp == 0) ? tp : negs[((size_t)b * NEG + (cp - 1)) * TT + tp];
    off[j] = (unsigned)(((size_t)b * TT + u) * CC) * 4u;
  }
  const char* tlb = (const char*)tl;

  int rowb[NSTEPS], rsw[NSTEPS];
#pragma unroll
  for (int i = 0; i < NSTEPS; ++i) {
    const int r = tloc + COPIES - i;
    rowb[i] = r * CC;
    rsw[i] = r & 7;
  }

  float acc[NSTEPS][NCP] = {};
  float tsum[NCP] = {};
  __syncthreads();

  float4 tg[NCP];
#pragma unroll
  for (int j = 0; j < NCP; ++j)
    tg[j] = *reinterpret_cast<const float4*>(tlb + off[j] + (unsigned)(kg << 4));
#pragma unroll
  for (int c4 = 0; c4 < 16; ++c4) {
    float4 tgn[NCP];
    if (c4 < 15) {
      const unsigned e4n = (unsigned)((((c4 + 1) << 2) | kg) << 4);
#pragma unroll
      for (int j = 0; j < NCP; ++j)
        tgn[j] = *reinterpret_cast<const float4*>(tlb + off[j] + e4n);
    }
#pragma unroll
    for (int j = 0; j < NCP; ++j)
      tsum[j] += (tg[j].x + tg[j].y) + (tg[j].z + tg[j].w);
    const int e4 = (c4 << 2) | kg;
#pragma unroll
    for (int i = 0; i < NSTEPS; ++i) {
      const float4 cx = *reinterpret_cast<const float4*>(&lds[rowb[i] + ((e4 ^ rsw[i]) << 2)]);
#pragma unroll
      for (int j = 0; j < NCP; ++j) {
        acc[i][j] = fmaf(cx.x, tg[j].x, acc[i][j]);
        acc[i][j] = fmaf(cx.y, tg[j].y, acc[i][j]);
        acc[i][j] = fmaf(cx.z, tg[j].z, acc[i][j]);
        acc[i][j] = fmaf(cx.w, tg[j].w, acc[i][j]);
      }
    }
    if (c4 < 15) {
#pragma unroll
      for (int j = 0; j < NCP; ++j) tg[j] = tgn[j];
    }
  }

#pragma unroll
  for (int i = 0; i < NSTEPS; ++i)
#pragma unroll
    for (int j = 0; j < NCP; ++j) {
      acc[i][j] += __shfl_xor(acc[i][j], 1);
      acc[i][j] += __shfl_xor(acc[i][j], 2);
    }
#pragma unroll
  for (int j = 0; j < NCP; ++j) {
    tsum[j] += __shfl_xor(tsum[j], 1);
    tsum[j] += __shfl_xor(tsum[j], 2);
  }

  __syncthreads();
  float* sd = lds;                       // [16*12][13]
  float* ts = lds + TP * NSTEPS * 13;    // [16][13]
  if (kg == 0) {
#pragma unroll
    for (int j = 0; j < NCP; ++j) {
      const int cp = ch * 3 + j;
      if (cp <= 10) {
        ts[tloc * 13 + cp] = tsum[j];
#pragma unroll
        for (int i = 0; i < NSTEPS; ++i) sd[(tloc * NSTEPS + i) * 13 + cp] = acc[i][j];
      }
    }
  }
  __syncthreads();

  float contrib = 0.f;
  if (tid < TP * NSTEPS) {
    const int tt = tid / NSTEPS;
    const int i = tid - tt * NSTEPS;
    if (i <= tp0 + tt) {
      const float w = Ws[i], bbias = bs[i];
      const float* drow = &sd[tid * 13];
      const float* trow = &ts[tt * 13];
      float lg[COPIES];
      float m = -INFINITY;
#pragma unroll
      for (int cp = 0; cp < COPIES; ++cp) {
        lg[cp] = fmaf(w, drow[cp], bbias * trow[cp]);
        m = fmaxf(m, lg[cp]);
      }
      float s = 0.f;
#pragma unroll
      for (int cp = 0; cp < COPIES; ++cp) s += expf(lg[cp] - m);
      contrib = m + logf(s) - lg[0];
    }
  }

  __syncthreads();
  lds[tid] = contrib;
  __syncthreads();
  for (int s = 128; s > 0; s >>= 1) {
    if (tid < s) lds[tid] += lds[tid + s];
    __syncthreads();
  }
  if (tid == 0) partials[wg] = lds[0];
}

#define NBLK (BB * (TT / TP))  // 2048
// ---------------- Kernel 3: deterministic reduction of block partials (double accum)
__global__ __launch_bounds__(256) void reduce_kernel(const float* __restrict__ partials,
                                                     float* __restrict__ out) {
  __shared__ double sred[256];
  double acc = 0.0;
  for (int idx = threadIdx.x; idx < NBLK; idx += 256) acc += (double)partials[idx];
  sred[threadIdx.x] = acc;
  __syncthreads();
  for (int s = 128; s > 0; s >>= 1) {
    if (threadIdx.x < s) sred[threadIdx.x] += sred[threadIdx.x + s];
    __syncthreads();
  }
  if (threadIdx.x == 0) out[0] = (float)sred[0];
}

extern "C" void kernel_launch(void* const* d_in, const int* in_sizes, int n_in,
                              void* d_out, int out_size, void* d_ws, size_t ws_size,
                              hipStream_t stream) {
  const float* true_latent = (const float*)d_in[0];     // [BB,TT,FF]
  const float* context_latent = (const float*)d_in[1];  // [BB,TT,CC]
  const float* Wl = (const float*)d_in[2];              // [FF,CC]
  const float* bl = (const float*)d_in[3];              // [CC]
  const float* Ws = (const float*)d_in[4];              // [NSTEPS]
  const float* bs = (const float*)d_in[5];              // [NSTEPS]
  const int* negs = (const int*)d_in[6];                // [BB,NEG,TT]

  float* tl = (float*)d_ws;                                                    // 32 MB
  float* partials = (float*)((char*)d_ws + (size_t)MM * CC * sizeof(float));   // 8 KB

  dim3 g1(MM / 128, CC / 64);
  proj_gemm_kernel<<<g1, 256, 0, stream>>>(true_latent, Wl, bl, tl);
  cpc_loss_kernel<<<NBLK, 256, 0, stream>>>(context_latent, tl, negs, Ws, bs, partials);
  reduce_kernel<<<1, 256, 0, stream>>>(partials, (float*)d_out);
}